// Round 1
// baseline (89.105 us; speedup 1.0000x reference)
//
#include <hip/hip_runtime.h>

#define HW 128
#define PLANE (HW * HW)      // 16384
#define HD 32                // head_dim
#define NHEAD 4
#define SCALE 0.17677669529663687f   // 32^-0.5

__global__ __launch_bounds__(256) void natt3x3_kernel(
    const float* __restrict__ q,
    const float* __restrict__ k,
    const float* __restrict__ v,
    float* __restrict__ out) {
  const int tid = threadIdx.x;
  const int x  = tid & (HW - 1);
  const int yl = tid >> 7;                 // 0..1 (two rows per block)
  const int bid = blockIdx.x;              // ((b*4 + head) * 64) + y2
  const int y    = ((bid & 63) << 1) | yl;
  const int head = (bid >> 6) & 3;
  const int b    = bid >> 8;

  const size_t chan0 = (size_t)(b * 128 + head * HD) * PLANE;
  const int pix = y * HW + x;

  // Clamped neighbor offsets (safe addresses); validity handled via masks.
  int yr[3], xo[3];
#pragma unroll
  for (int i = 0; i < 3; ++i) {
    int yy = y + i - 1; yy = yy < 0 ? 0 : (yy > HW - 1 ? HW - 1 : yy);
    yr[i] = yy * HW;
    int xx = x + i - 1; xx = xx < 0 ? 0 : (xx > HW - 1 ? HW - 1 : xx);
    xo[i] = xx;
  }
  float mask[9];
#pragma unroll
  for (int dy = 0; dy < 3; ++dy)
#pragma unroll
    for (int dx = 0; dx < 3; ++dx) {
      bool ok = ((unsigned)(y + dy - 1) < (unsigned)HW) &&
                ((unsigned)(x + dx - 1) < (unsigned)HW);
      mask[dy * 3 + dx] = ok ? 1.f : 0.f;
    }

  // ---- load q (coalesced across x) ----
  float qreg[HD];
  const float* qp = q + chan0 + pix;
#pragma unroll
  for (int c = 0; c < HD; ++c) qreg[c] = qp[(size_t)c * PLANE];

  // ---- attention logits: 9 dots over 32 channels ----
  float logit[9];
#pragma unroll
  for (int i = 0; i < 9; ++i) logit[i] = 0.f;
  const float* kp0 = k + chan0;
#pragma unroll 4
  for (int c = 0; c < HD; ++c) {
    const float* kc = kp0 + (size_t)c * PLANE;
    const float qc = qreg[c];
#pragma unroll
    for (int dy = 0; dy < 3; ++dy) {
      const float* kr = kc + yr[dy];
#pragma unroll
      for (int dx = 0; dx < 3; ++dx) {
        logit[dy * 3 + dx] += qc * kr[xo[dx]];
      }
    }
  }

  // ---- mask (OOB -> exact 0 logit, matching zero-padded K), softmax ----
  float m = -1e30f;
#pragma unroll
  for (int i = 0; i < 9; ++i) {
    float l = logit[i] * mask[i] * SCALE;
    logit[i] = l;
    m = fmaxf(m, l);
  }
  float sum = 0.f;
#pragma unroll
  for (int i = 0; i < 9; ++i) {
    float e = __expf(logit[i] - m);
    logit[i] = e;
    sum += e;
  }
  const float inv = 1.f / sum;
#pragma unroll
  for (int i = 0; i < 9; ++i) logit[i] *= inv * mask[i];  // fold mask into weights

  // ---- PV + ReLU + store (float4, 16B-aligned) ----
  const float* vp0 = v + chan0;
  float* op = out + ((size_t)(b * PLANE + pix)) * 128 + head * HD;
#pragma unroll 2
  for (int c = 0; c < HD; c += 4) {
    float4 o;
    float* oe = reinterpret_cast<float*>(&o);
#pragma unroll
    for (int cc = 0; cc < 4; ++cc) {
      const float* vc = vp0 + (size_t)(c + cc) * PLANE;
      float a = 0.f;
#pragma unroll
      for (int dy = 0; dy < 3; ++dy) {
        const float* vr = vc + yr[dy];
#pragma unroll
        for (int dx = 0; dx < 3; ++dx) a += logit[dy * 3 + dx] * vr[xo[dx]];
      }
      oe[cc] = fmaxf(a, 0.f);
    }
    *reinterpret_cast<float4*>(op + c) = o;
  }
}

extern "C" void kernel_launch(void* const* d_in, const int* in_sizes, int n_in,
                              void* d_out, int out_size, void* d_ws, size_t ws_size,
                              hipStream_t stream) {
  const float* q = (const float*)d_in[0];
  const float* k = (const float*)d_in[1];
  const float* v = (const float*)d_in[2];
  float* out = (float*)d_out;
  // grid: B(4) * heads(4) * (H/2 = 64) blocks, 256 threads (2 rows of 128)
  natt3x3_kernel<<<4 * NHEAD * (HW / 2), 256, 0, stream>>>(q, k, v, out);
}

// Round 2
// 77.766 us; speedup vs baseline: 1.1458x; 1.1458x over previous
//
#include <hip/hip_runtime.h>

#define HW 128
#define PLANE (HW * HW)      // 16384
#define HD 32                // head_dim
#define SCALE 0.17677669529663687f   // 32^-0.5

// 2 threads per pixel, 16 channels each. Block = 256 threads = 1 row of 128
// pixels x 2 channel-halves. Grid = B(4) * heads(4) * rows(128) = 2048 blocks
// = 8192 waves = 100% of MI355X wave slots (fixes the 50% grid cap of R1).
__global__ __launch_bounds__(256) void natt3x3_kernel(
    const float* __restrict__ q,
    const float* __restrict__ k,
    const float* __restrict__ v,
    float* __restrict__ out) {
  const int tid = threadIdx.x;
  const int h2 = tid & 1;              // channel half: 0 -> c 0..15, 1 -> c 16..31
  const int x  = tid >> 1;             // pixel x, 0..127
  const int bid = blockIdx.x;          // ((b*4 + head) * 128) + y
  const int y    = bid & 127;
  const int head = (bid >> 7) & 3;
  const int b    = bid >> 9;

  const size_t chan0 = (size_t)(b * 128 + head * HD + h2 * 16) * PLANE;
  const int pix = y * HW + x;

  // Clamped neighbor offsets (safe addresses); validity handled via masks.
  int yr[3], xo[3];
#pragma unroll
  for (int i = 0; i < 3; ++i) {
    int yy = y + i - 1; yy = yy < 0 ? 0 : (yy > HW - 1 ? HW - 1 : yy);
    yr[i] = yy * HW;
    int xx = x + i - 1; xx = xx < 0 ? 0 : (xx > HW - 1 ? HW - 1 : xx);
    xo[i] = xx;
  }
  float mask[9];
#pragma unroll
  for (int dy = 0; dy < 3; ++dy)
#pragma unroll
    for (int dx = 0; dx < 3; ++dx) {
      bool ok = ((unsigned)(y + dy - 1) < (unsigned)HW) &&
                ((unsigned)(x + dx - 1) < (unsigned)HW);
      mask[dy * 3 + dx] = ok ? 1.f : 0.f;
    }

  // ---- load q for my 16 channels (SCALE folded in) ----
  float qreg[16];
  const float* qp = q + chan0 + pix;
#pragma unroll
  for (int c = 0; c < 16; ++c) qreg[c] = qp[(size_t)c * PLANE] * SCALE;

  // ---- partial logits over my 16 channels ----
  float logit[9];
#pragma unroll
  for (int i = 0; i < 9; ++i) logit[i] = 0.f;
  const float* kp0 = k + chan0;
#pragma unroll 4
  for (int c = 0; c < 16; ++c) {
    const float* kc = kp0 + (size_t)c * PLANE;
    const float qc = qreg[c];
#pragma unroll
    for (int dy = 0; dy < 3; ++dy) {
      const float* kr = kc + yr[dy];
#pragma unroll
      for (int dx = 0; dx < 3; ++dx) {
        logit[dy * 3 + dx] += qc * kr[xo[dx]];
      }
    }
  }

  // ---- combine with partner thread (same pixel, other 16 channels) ----
#pragma unroll
  for (int i = 0; i < 9; ++i) logit[i] += __shfl_xor(logit[i], 1);

  // ---- mask (OOB -> exact 0 logit, matching zero-padded K), softmax ----
  float m = -1e30f;
#pragma unroll
  for (int i = 0; i < 9; ++i) {
    float l = logit[i] * mask[i];
    logit[i] = l;
    m = fmaxf(m, l);
  }
  float sum = 0.f;
#pragma unroll
  for (int i = 0; i < 9; ++i) {
    float e = __expf(logit[i] - m);
    logit[i] = e;
    sum += e;
  }
  const float inv = 1.f / sum;
#pragma unroll
  for (int i = 0; i < 9; ++i) logit[i] *= inv * mask[i];  // fold mask into weights

  // ---- PV + ReLU + store (my 16 channels, 4x float4) ----
  const float* vp0 = v + chan0;
  float* op = out + ((size_t)(b * PLANE + pix)) * 128 + head * HD + h2 * 16;
#pragma unroll
  for (int c = 0; c < 16; c += 4) {
    float4 o;
    float* oe = reinterpret_cast<float*>(&o);
#pragma unroll
    for (int cc = 0; cc < 4; ++cc) {
      const float* vc = vp0 + (size_t)(c + cc) * PLANE;
      float a = 0.f;
#pragma unroll
      for (int dy = 0; dy < 3; ++dy) {
        const float* vr = vc + yr[dy];
#pragma unroll
        for (int dx = 0; dx < 3; ++dx) a += logit[dy * 3 + dx] * vr[xo[dx]];
      }
      oe[cc] = fmaxf(a, 0.f);
    }
    *reinterpret_cast<float4*>(op + c) = o;
  }
}

extern "C" void kernel_launch(void* const* d_in, const int* in_sizes, int n_in,
                              void* d_out, int out_size, void* d_ws, size_t ws_size,
                              hipStream_t stream) {
  const float* q = (const float*)d_in[0];
  const float* k = (const float*)d_in[1];
  const float* v = (const float*)d_in[2];
  float* out = (float*)d_out;
  // grid: B(4) * heads(4) * rows(128) = 2048 blocks, 256 threads each
  natt3x3_kernel<<<2048, 256, 0, stream>>>(q, k, v, out);
}

// Round 3
// 44.039 us; speedup vs baseline: 2.0233x; 1.7658x over previous
//
#include <hip/hip_runtime.h>

#define HW 128
#define PLANE (HW * HW)      // 16384
#define SCALE 0.17677669529663687f   // 32^-0.5

// One thread = 4-pixel x-strip x 16 channels (h2 half). One wave = one image
// row (32 strips x 2 halves). Block = 4 waves = 4 rows. All k/v loads are
// float4; x-neighbors via in-register quad + __shfl_up/down(2); logit halves
// combined via __shfl_xor(1). Grid = 4b*4h*32 ytiles = 512 blocks.
__global__ __launch_bounds__(256) void natt3x3_kernel(
    const float* __restrict__ q,
    const float* __restrict__ k,
    const float* __restrict__ v,
    float* __restrict__ out) {
  const int tid  = threadIdx.x;
  const int lane = tid & 63;
  const int w    = tid >> 6;            // wave index in block = row in tile
  const int h2   = lane & 1;            // channel half
  const int s    = lane >> 1;           // strip 0..31
  const int x0   = s << 2;              // first pixel x of strip
  const int bid  = blockIdx.x;          // ((b*4+head)*32 + ytile)
  const int ytile = bid & 31;
  const int head  = (bid >> 5) & 3;
  const int b     = bid >> 7;
  const int y     = (ytile << 2) | w;

  const size_t cbase = (size_t)(b * 128 + head * 32 + h2 * 16) * PLANE;

  int yrow[3];
#pragma unroll
  for (int dy = 0; dy < 3; ++dy) {
    int yy = y + dy - 1; yy = yy < 0 ? 0 : (yy > HW - 1 ? HW - 1 : yy);
    yrow[dy] = yy * HW;
  }

  // ---- QK: partial logits over my 16 channels, 4 pixels ----
  float l[4][9];
#pragma unroll
  for (int i = 0; i < 4; ++i)
#pragma unroll
    for (int j = 0; j < 9; ++j) l[i][j] = 0.f;

  const float* kb = k + cbase;
  const float* qb = q + cbase + y * HW + x0;

#pragma unroll 4
  for (int ch = 0; ch < 16; ++ch) {
    const float* kc = kb + (size_t)ch * PLANE;
    float4 qv = *reinterpret_cast<const float4*>(qb + (size_t)ch * PLANE);
    qv.x *= SCALE; qv.y *= SCALE; qv.z *= SCALE; qv.w *= SCALE;
    const float qa[4] = {qv.x, qv.y, qv.z, qv.w};
#pragma unroll
    for (int dy = 0; dy < 3; ++dy) {
      float4 kv = *reinterpret_cast<const float4*>(kc + yrow[dy] + x0);
      float n0 = __shfl_up(kv.w, 2);     // left neighbor (prev strip, same half)
      float n5 = __shfl_down(kv.x, 2);   // right neighbor
      const float n[6] = {n0, kv.x, kv.y, kv.z, kv.w, n5};
#pragma unroll
      for (int i = 0; i < 4; ++i)
#pragma unroll
        for (int j = 0; j < 3; ++j)
          l[i][dy * 3 + j] += qa[i] * n[i + j];
    }
  }

  // ---- combine channel halves ----
#pragma unroll
  for (int i = 0; i < 4; ++i)
#pragma unroll
    for (int j = 0; j < 9; ++j) l[i][j] += __shfl_xor(l[i][j], 1);

  // ---- mask + softmax per pixel; fold mask back into weights ----
#pragma unroll
  for (int i = 0; i < 4; ++i) {
    const int xp = x0 + i;
    float mk[9];
#pragma unroll
    for (int dy = 0; dy < 3; ++dy)
#pragma unroll
      for (int dx = 0; dx < 3; ++dx) {
        bool ok = ((unsigned)(y + dy - 1) < (unsigned)HW) &&
                  ((unsigned)(xp + dx - 1) < (unsigned)HW);
        mk[dy * 3 + dx] = ok ? 1.f : 0.f;
      }
    float m = -1e30f;
#pragma unroll
    for (int j = 0; j < 9; ++j) {
      float t = l[i][j] * mk[j];
      l[i][j] = t;
      m = fmaxf(m, t);
    }
    float sum = 0.f;
#pragma unroll
    for (int j = 0; j < 9; ++j) {
      float e = __expf(l[i][j] - m);
      l[i][j] = e;
      sum += e;
    }
    float inv = 1.f / sum;
#pragma unroll
    for (int j = 0; j < 9; ++j) l[i][j] *= inv * mk[j];
  }

  // ---- PV + ReLU + store: channel groups of 4 ----
  const float* vb = v + cbase;
  const size_t obase = ((size_t)(b * PLANE + y * HW)) * 128 + head * 32 + h2 * 16;
#pragma unroll
  for (int cg = 0; cg < 4; ++cg) {
    float acc[4][4];
#pragma unroll
    for (int i = 0; i < 4; ++i)
#pragma unroll
      for (int c = 0; c < 4; ++c) acc[i][c] = 0.f;
#pragma unroll
    for (int chl = 0; chl < 4; ++chl) {
      const float* vc = vb + (size_t)(cg * 4 + chl) * PLANE;
#pragma unroll
      for (int dy = 0; dy < 3; ++dy) {
        float4 vv = *reinterpret_cast<const float4*>(vc + yrow[dy] + x0);
        float n0 = __shfl_up(vv.w, 2);
        float n5 = __shfl_down(vv.x, 2);
        const float n[6] = {n0, vv.x, vv.y, vv.z, vv.w, n5};
#pragma unroll
        for (int i = 0; i < 4; ++i)
#pragma unroll
          for (int j = 0; j < 3; ++j)
            acc[i][chl] += l[i][dy * 3 + j] * n[i + j];
      }
    }
#pragma unroll
    for (int i = 0; i < 4; ++i) {
      float4 o;
      o.x = fmaxf(acc[i][0], 0.f);
      o.y = fmaxf(acc[i][1], 0.f);
      o.z = fmaxf(acc[i][2], 0.f);
      o.w = fmaxf(acc[i][3], 0.f);
      *reinterpret_cast<float4*>(out + obase + (size_t)(x0 + i) * 128 + cg * 4) = o;
    }
  }
}

extern "C" void kernel_launch(void* const* d_in, const int* in_sizes, int n_in,
                              void* d_out, int out_size, void* d_ws, size_t ws_size,
                              hipStream_t stream) {
  const float* q = (const float*)d_in[0];
  const float* k = (const float*)d_in[1];
  const float* v = (const float*)d_in[2];
  float* out = (float*)d_out;
  natt3x3_kernel<<<512, 256, 0, stream>>>(q, k, v, out);
}

// Round 4
// 33.441 us; speedup vs baseline: 2.6646x; 1.3169x over previous
//
#include <hip/hip_runtime.h>

#define HW 128
#define PLANE (HW * HW)      // 16384
#define SCALE 0.17677669529663687f   // 32^-0.5

// One thread = 4-pixel x-strip x 16 channels. lane = (strip<<1)|h2; one wave
// = one image row. Thread's channels: g*8 + h2*4 + {0..3} for g=0..3 (so the
// h2 lane-pair's 16B stores are 32B-contiguous -> no write amplification).
// QK and PV are software-pipelined in 4 channel-groups with double-buffered
// float4 load batches (16 loads/batch, 2 batches in flight = 128 VGPRs).
__global__ __launch_bounds__(256, 2) void natt3x3_kernel(
    const float* __restrict__ q,
    const float* __restrict__ k,
    const float* __restrict__ v,
    float* __restrict__ out) {
  const int tid  = threadIdx.x;
  const int lane = tid & 63;
  const int w    = tid >> 6;            // wave index in block = row in tile
  const int h2   = lane & 1;            // channel sub-quad selector
  const int s    = lane >> 1;           // strip 0..31
  const int x0   = s << 2;              // first pixel x of strip
  const int bid  = blockIdx.x;          // ((b*4+head)*32 + ytile)
  const int ytile = bid & 31;
  const int head  = (bid >> 5) & 3;
  const int b     = bid >> 7;
  const int y     = (ytile << 2) | w;

  // channel base: b*128 + head*32 + h2*4 ; group g adds g*8
  const size_t cbase = (size_t)(b * 128 + head * 32 + h2 * 4) * PLANE;
  const int yx = y * HW + x0;

  int yrow[3];
#pragma unroll
  for (int dy = 0; dy < 3; ++dy) {
    int yy = y + dy - 1; yy = yy < 0 ? 0 : (yy > HW - 1 ? HW - 1 : yy);
    yrow[dy] = yy * HW;
  }

  float l[4][9];
#pragma unroll
  for (int i = 0; i < 4; ++i)
#pragma unroll
    for (int j = 0; j < 9; ++j) l[i][j] = 0.f;

  float4 qv[2][4];
  float4 kv[2][3][4];
  float4 vv[2][3][4];

#define QK_LOAD(B, G) do {                                                   \
    const size_t cb = cbase + (size_t)((G) * 8) * PLANE;                     \
    const float* qg = q + cb + yx;                                           \
    const float* kg = k + cb;                                                \
    _Pragma("unroll")                                                        \
    for (int c = 0; c < 4; ++c) {                                            \
      qv[B][c] = *reinterpret_cast<const float4*>(qg + (size_t)c * PLANE);   \
      _Pragma("unroll")                                                      \
      for (int dy = 0; dy < 3; ++dy)                                         \
        kv[B][dy][c] = *reinterpret_cast<const float4*>(                     \
            kg + (size_t)c * PLANE + yrow[dy] + x0);                         \
    }                                                                        \
  } while (0)

#define QK_COMP(B) do {                                                      \
    _Pragma("unroll")                                                        \
    for (int c = 0; c < 4; ++c) {                                            \
      const float qa[4] = {qv[B][c].x * SCALE, qv[B][c].y * SCALE,           \
                           qv[B][c].z * SCALE, qv[B][c].w * SCALE};          \
      _Pragma("unroll")                                                      \
      for (int dy = 0; dy < 3; ++dy) {                                       \
        float4 kq = kv[B][dy][c];                                            \
        float n0 = __shfl_up(kq.w, 2);                                       \
        float n5 = __shfl_down(kq.x, 2);                                     \
        const float n[6] = {n0, kq.x, kq.y, kq.z, kq.w, n5};                 \
        _Pragma("unroll")                                                    \
        for (int i = 0; i < 4; ++i)                                          \
          _Pragma("unroll")                                                  \
          for (int j = 0; j < 3; ++j)                                        \
            l[i][dy * 3 + j] += qa[i] * n[i + j];                            \
      }                                                                      \
    }                                                                        \
  } while (0)

#define PV_LOAD(B, G) do {                                                   \
    const size_t cb = cbase + (size_t)((G) * 8) * PLANE;                     \
    const float* vg = v + cb;                                                \
    _Pragma("unroll")                                                        \
    for (int c = 0; c < 4; ++c)                                              \
      _Pragma("unroll")                                                      \
      for (int dy = 0; dy < 3; ++dy)                                         \
        vv[B][dy][c] = *reinterpret_cast<const float4*>(                     \
            vg + (size_t)c * PLANE + yrow[dy] + x0);                         \
  } while (0)

#define PV_COMP(B, G) do {                                                   \
    float acc[4][4];                                                         \
    _Pragma("unroll")                                                        \
    for (int i = 0; i < 4; ++i)                                              \
      _Pragma("unroll")                                                      \
      for (int c = 0; c < 4; ++c) acc[i][c] = 0.f;                           \
    _Pragma("unroll")                                                        \
    for (int c = 0; c < 4; ++c)                                              \
      _Pragma("unroll")                                                      \
      for (int dy = 0; dy < 3; ++dy) {                                       \
        float4 vq = vv[B][dy][c];                                            \
        float n0 = __shfl_up(vq.w, 2);                                       \
        float n5 = __shfl_down(vq.x, 2);                                     \
        const float n[6] = {n0, vq.x, vq.y, vq.z, vq.w, n5};                 \
        _Pragma("unroll")                                                    \
        for (int i = 0; i < 4; ++i)                                          \
          _Pragma("unroll")                                                  \
          for (int j = 0; j < 3; ++j)                                        \
            acc[i][c] += l[i][dy * 3 + j] * n[i + j];                        \
      }                                                                      \
    _Pragma("unroll")                                                        \
    for (int i = 0; i < 4; ++i) {                                            \
      float4 o;                                                              \
      o.x = fmaxf(acc[i][0], 0.f);                                           \
      o.y = fmaxf(acc[i][1], 0.f);                                           \
      o.z = fmaxf(acc[i][2], 0.f);                                           \
      o.w = fmaxf(acc[i][3], 0.f);                                           \
      *reinterpret_cast<float4*>(out + obase + (size_t)(x0 + i) * 128 +      \
                                 (G) * 8) = o;                               \
    }                                                                        \
  } while (0)

  // ---- QK: 4 channel-groups, double-buffered ----
  QK_LOAD(0, 0);
  QK_LOAD(1, 1);
  QK_COMP(0);
  QK_LOAD(0, 2);
  QK_COMP(1);
  QK_LOAD(1, 3);
  QK_COMP(0);
  QK_COMP(1);

  // ---- prefetch first V batch under the softmax ----
  PV_LOAD(0, 0);

  // ---- combine channel halves (lane pair) ----
#pragma unroll
  for (int i = 0; i < 4; ++i)
#pragma unroll
    for (int j = 0; j < 9; ++j) l[i][j] += __shfl_xor(l[i][j], 1);

  // ---- mask + softmax per pixel; fold mask back into weights ----
#pragma unroll
  for (int i = 0; i < 4; ++i) {
    const int xp = x0 + i;
    float mk[9];
#pragma unroll
    for (int dy = 0; dy < 3; ++dy)
#pragma unroll
      for (int dx = 0; dx < 3; ++dx) {
        bool ok = ((unsigned)(y + dy - 1) < (unsigned)HW) &&
                  ((unsigned)(xp + dx - 1) < (unsigned)HW);
        mk[dy * 3 + dx] = ok ? 1.f : 0.f;
      }
    float m = -1e30f;
#pragma unroll
    for (int j = 0; j < 9; ++j) {
      float t = l[i][j] * mk[j];
      l[i][j] = t;
      m = fmaxf(m, t);
    }
    float sum = 0.f;
#pragma unroll
    for (int j = 0; j < 9; ++j) {
      float e = __expf(l[i][j] - m);
      l[i][j] = e;
      sum += e;
    }
    float inv = 1.f / sum;
#pragma unroll
    for (int j = 0; j < 9; ++j) l[i][j] *= inv * mk[j];
  }

  const size_t obase = ((size_t)(b * PLANE + y * HW)) * 128 + head * 32 + h2 * 4;

  // ---- PV: 4 channel-groups, double-buffered, stores 32B-paired ----
  PV_LOAD(1, 1);
  PV_COMP(0, 0);
  PV_LOAD(0, 2);
  PV_COMP(1, 1);
  PV_LOAD(1, 3);
  PV_COMP(0, 2);
  PV_COMP(1, 3);

#undef QK_LOAD
#undef QK_COMP
#undef PV_LOAD
#undef PV_COMP
}

extern "C" void kernel_launch(void* const* d_in, const int* in_sizes, int n_in,
                              void* d_out, int out_size, void* d_ws, size_t ws_size,
                              hipStream_t stream) {
  const float* q = (const float*)d_in[0];
  const float* k = (const float*)d_in[1];
  const float* v = (const float*)d_in[2];
  float* out = (float*)d_out;
  natt3x3_kernel<<<512, 256, 0, stream>>>(q, k, v, out);
}